// Round 1
// baseline (328.064 us; speedup 1.0000x reference)
//
#include <hip/hip_runtime.h>

#define H 1024
#define HH (H * H)          // 1048576 per channel plane
#define CHW (3 * HH)        // 3145728 per image
#define NB 256

__device__ __forceinline__ float clamp01(float x) { return fminf(fmaxf(x, 0.0f), 1.0f); }

// ---------------------------------------------------------------------------
// Stage 1: elementwise masking.
// out0 = target_masked/255 = clip((t+1)/2,0,1) * (mask_tar/255)
// out1 = ref_masked/255    = clip((r+1)/2,0,1) * (mask_src/255)
// out2 = input_masked/255  = clip(i,0,1)       * (mask_src/255)
// out3 = out1 (base for the scatter of matched values)
// One thread per 4 pixels (float4), 3 channels per thread.
// ---------------------------------------------------------------------------
__global__ void k_elementwise(const float4* __restrict__ inp,
                              const float4* __restrict__ tar,
                              const float4* __restrict__ rfp,
                              const float4* __restrict__ msrc,
                              const float4* __restrict__ mtar,
                              float4* __restrict__ out0, float4* __restrict__ out1,
                              float4* __restrict__ out2, float4* __restrict__ out3)
{
    int p = blockIdx.x * blockDim.x + threadIdx.x;
    if (p >= HH / 4) return;
    float4 ms4 = msrc[p], mt4 = mtar[p];
    // true division: 255.0f/255.0f == 1.0f exactly (mul by 1/255f would give 1+ulp)
    float msx = ms4.x / 255.0f, msy = ms4.y / 255.0f, msz = ms4.z / 255.0f, msw = ms4.w / 255.0f;
    float mtx = mt4.x / 255.0f, mty = mt4.y / 255.0f, mtz = mt4.z / 255.0f, mtw = mt4.w / 255.0f;
#pragma unroll
    for (int c = 0; c < 3; ++c) {
        int q = c * (HH / 4) + p;
        float4 t = tar[q], r = rfp[q], iv = inp[q];
        float4 o0, o1, o2;
        o0.x = clamp01((t.x + 1.0f) * 0.5f) * mtx;
        o0.y = clamp01((t.y + 1.0f) * 0.5f) * mty;
        o0.z = clamp01((t.z + 1.0f) * 0.5f) * mtz;
        o0.w = clamp01((t.w + 1.0f) * 0.5f) * mtw;
        o1.x = clamp01((r.x + 1.0f) * 0.5f) * msx;
        o1.y = clamp01((r.y + 1.0f) * 0.5f) * msy;
        o1.z = clamp01((r.z + 1.0f) * 0.5f) * msz;
        o1.w = clamp01((r.w + 1.0f) * 0.5f) * msw;
        o2.x = clamp01(iv.x) * msx;
        o2.y = clamp01(iv.y) * msy;
        o2.z = clamp01(iv.z) * msz;
        o2.w = clamp01(iv.w) * msw;
        out0[q] = o0;
        out1[q] = o1;
        out3[q] = o1;
        out2[q] = o2;
    }
}

// ---------------------------------------------------------------------------
// Stage 2: LDS-privatized histograms of gathered samples.
// ghist[0..767]   = hist of ref_masked  (dst) per channel
// ghist[768..1535]= hist of target_masked (ref) per channel
// Recompute masked values from raw inputs (bit-exact bins vs reference).
// ---------------------------------------------------------------------------
__global__ void k_hist(const float* __restrict__ rfp, const float* __restrict__ tar,
                       const float* __restrict__ msrc, const float* __restrict__ mtar,
                       const int* __restrict__ i0, const int* __restrict__ i1,
                       const int* __restrict__ i2, const int* __restrict__ i3,
                       unsigned int* __restrict__ ghist, int n)
{
    __shared__ unsigned int h[2 * 3 * NB];
    for (int i = threadIdx.x; i < 2 * 3 * NB; i += blockDim.x) h[i] = 0u;
    __syncthreads();

    for (int k = blockIdx.x * blockDim.x + threadIdx.x; k < n; k += gridDim.x * blockDim.x) {
        int pd = i0[k] * H + i1[k];
        int pr = i2[k] * H + i3[k];
        float md = msrc[pd] / 255.0f;
        float mr = mtar[pr] / 255.0f;
#pragma unroll
        for (int c = 0; c < 3; ++c) {
            float rv = rfp[c * HH + pd];
            float v  = clamp01((rv + 1.0f) * 0.5f) * 255.0f * md;   // ref_masked value
            int b = min(max((int)v, 0), NB - 1);
            atomicAdd(&h[c * NB + b], 1u);
            float tv = tar[c * HH + pr];
            float w  = clamp01((tv + 1.0f) * 0.5f) * 255.0f * mr;   // target_masked value
            int b2 = min(max((int)w, 0), NB - 1);
            atomicAdd(&h[3 * NB + c * NB + b2], 1u);
        }
    }
    __syncthreads();
    for (int i = threadIdx.x; i < 2 * 3 * NB; i += blockDim.x) {
        unsigned int v = h[i];
        if (v) atomicAdd(&ghist[i], v);
    }
}

// ---------------------------------------------------------------------------
// Stage 3: cdfs + transfer tables (single block).
// cdf: sequential int prefix sum -> float divide by total (bit-exact vs jnp).
// table[i] = first j in [0,254] with cdf_dst[i] in [cdf_ref[j], cdf_ref[j+1]],
//            then +1; identity if none; table[255]=255.
// ---------------------------------------------------------------------------
__global__ void k_tables(const unsigned int* __restrict__ ghist, float* __restrict__ table)
{
    __shared__ float cdfd[3][NB];
    __shared__ float cdfr[3][NB];
    int t = threadIdx.x;
    if (t < 6) {
        int which = t / 3;   // 0 = dst hist, 1 = ref hist
        int c = t % 3;
        const unsigned int* hs = ghist + which * 3 * NB + c * NB;
        unsigned int tot = 0;
        for (int i = 0; i < NB; ++i) tot += hs[i];
        float ft = (float)tot;
        float* dst = which ? cdfr[c] : cdfd[c];
        unsigned int s = 0;
        for (int i = 0; i < NB; ++i) {
            s += hs[i];
            dst[i] = (float)s / ft;
        }
    }
    __syncthreads();
    if (t < NB) {
#pragma unroll
        for (int c = 0; c < 3; ++c) {
            float r = cdfd[c][t];
            int tab = t;
            for (int j = 0; j < NB - 1; ++j) {
                if (r >= cdfr[c][j] && r <= cdfr[c][j + 1]) { tab = j + 1; break; }
            }
            if (t == NB - 1) tab = NB - 1;
            table[c * NB + t] = (float)tab;
        }
    }
}

// ---------------------------------------------------------------------------
// Stage 4: scatter matched values into out3.
// Duplicate (i0,i1) pairs write identical values -> benign race.
// ---------------------------------------------------------------------------
__global__ void k_scatter(const float* __restrict__ rfp, const float* __restrict__ msrc,
                          const int* __restrict__ i0, const int* __restrict__ i1,
                          const float* __restrict__ table, float* __restrict__ out3, int n)
{
    int k = blockIdx.x * blockDim.x + threadIdx.x;
    if (k >= n) return;
    int pd = i0[k] * H + i1[k];
    float md = msrc[pd] / 255.0f;
#pragma unroll
    for (int c = 0; c < 3; ++c) {
        float rv = rfp[c * HH + pd];
        float v  = clamp01((rv + 1.0f) * 0.5f) * 255.0f * md;
        int b = min(max((int)v, 0), NB - 1);
        out3[c * HH + pd] = table[c * NB + b] / 255.0f;
    }
}

// ---------------------------------------------------------------------------
// Stage 5: loss = mean |out2 - out3| over 3*H*H elements.
// ---------------------------------------------------------------------------
__global__ void k_loss(const float4* __restrict__ a, const float4* __restrict__ b,
                       float* __restrict__ loss)
{
    float s = 0.0f;
    int n4 = CHW / 4;
    for (int i = blockIdx.x * blockDim.x + threadIdx.x; i < n4; i += gridDim.x * blockDim.x) {
        float4 x = a[i], y = b[i];
        s += fabsf(x.x - y.x) + fabsf(x.y - y.y) + fabsf(x.z - y.z) + fabsf(x.w - y.w);
    }
#pragma unroll
    for (int off = 32; off > 0; off >>= 1) s += __shfl_down(s, off);
    __shared__ float ws[4];
    int lane = threadIdx.x & 63, w = threadIdx.x >> 6;
    if (lane == 0) ws[w] = s;
    __syncthreads();
    if (threadIdx.x == 0) {
        float tsum = ws[0] + ws[1] + ws[2] + ws[3];
        atomicAdd(loss, tsum * (1.0f / (float)CHW));
    }
}

extern "C" void kernel_launch(void* const* d_in, const int* in_sizes, int n_in,
                              void* d_out, int out_size, void* d_ws, size_t ws_size,
                              hipStream_t stream)
{
    const float* inp  = (const float*)d_in[0];
    const float* tar  = (const float*)d_in[1];
    const float* rfp  = (const float*)d_in[2];
    const float* msrc = (const float*)d_in[3];
    const float* mtar = (const float*)d_in[4];
    // d_in[5] = target_data_eye (unused by the reference computation)
    const int* i0 = (const int*)d_in[6];
    const int* i1 = (const int*)d_in[7];
    const int* i2 = (const int*)d_in[8];
    const int* i3 = (const int*)d_in[9];
    int n = in_sizes[6];

    float* out0 = (float*)d_out;
    float* out1 = out0 + CHW;
    float* out2 = out1 + CHW;
    float* out3 = out2 + CHW;
    float* loss = out3 + CHW;

    unsigned int* ghist = (unsigned int*)d_ws;            // 1536 u32
    float* table = (float*)((char*)d_ws + 1536 * sizeof(unsigned int)); // 768 f32

    hipMemsetAsync(d_ws, 0, 1536 * sizeof(unsigned int), stream);
    hipMemsetAsync(loss, 0, sizeof(float), stream);

    k_elementwise<<<(HH / 4 + 255) / 256, 256, 0, stream>>>(
        (const float4*)inp, (const float4*)tar, (const float4*)rfp,
        (const float4*)msrc, (const float4*)mtar,
        (float4*)out0, (float4*)out1, (float4*)out2, (float4*)out3);

    k_hist<<<256, 256, 0, stream>>>(rfp, tar, msrc, mtar, i0, i1, i2, i3, ghist, n);

    k_tables<<<1, 256, 0, stream>>>(ghist, table);

    k_scatter<<<(n + 255) / 256, 256, 0, stream>>>(rfp, msrc, i0, i1, table, out3, n);

    k_loss<<<768, 256, 0, stream>>>((const float4*)out2, (const float4*)out3, loss);
}

// Round 2
// 312.165 us; speedup vs baseline: 1.0509x; 1.0509x over previous
//
#include <hip/hip_runtime.h>

#define H 1024
#define HH (H * H)          // 1048576 per channel plane
#define CHW (3 * HH)        // 3145728 per image
#define NB 256

__device__ __forceinline__ float clamp01(float x) { return fminf(fmaxf(x, 0.0f), 1.0f); }

// ---------------------------------------------------------------------------
// Stage 1: elementwise masking.
// out0 = target_masked/255 = clip((t+1)/2,0,1) * (mask_tar/255)
// out1 = ref_masked/255    = clip((r+1)/2,0,1) * (mask_src/255)
// out2 = input_masked/255  = clip(i,0,1)       * (mask_src/255)
// out3 = out1 (base for the scatter of matched values)
// ---------------------------------------------------------------------------
__global__ void k_elementwise(const float4* __restrict__ inp,
                              const float4* __restrict__ tar,
                              const float4* __restrict__ rfp,
                              const float4* __restrict__ msrc,
                              const float4* __restrict__ mtar,
                              float4* __restrict__ out0, float4* __restrict__ out1,
                              float4* __restrict__ out2, float4* __restrict__ out3)
{
    int p = blockIdx.x * blockDim.x + threadIdx.x;
    if (p >= HH / 4) return;
    float4 ms4 = msrc[p], mt4 = mtar[p];
    // true division: 255.0f/255.0f == 1.0f exactly (mul by 1/255f would give 1+ulp)
    float msx = ms4.x / 255.0f, msy = ms4.y / 255.0f, msz = ms4.z / 255.0f, msw = ms4.w / 255.0f;
    float mtx = mt4.x / 255.0f, mty = mt4.y / 255.0f, mtz = mt4.z / 255.0f, mtw = mt4.w / 255.0f;
#pragma unroll
    for (int c = 0; c < 3; ++c) {
        int q = c * (HH / 4) + p;
        float4 t = tar[q], r = rfp[q], iv = inp[q];
        float4 o0, o1, o2;
        o0.x = clamp01((t.x + 1.0f) * 0.5f) * mtx;
        o0.y = clamp01((t.y + 1.0f) * 0.5f) * mty;
        o0.z = clamp01((t.z + 1.0f) * 0.5f) * mtz;
        o0.w = clamp01((t.w + 1.0f) * 0.5f) * mtw;
        o1.x = clamp01((r.x + 1.0f) * 0.5f) * msx;
        o1.y = clamp01((r.y + 1.0f) * 0.5f) * msy;
        o1.z = clamp01((r.z + 1.0f) * 0.5f) * msz;
        o1.w = clamp01((r.w + 1.0f) * 0.5f) * msw;
        o2.x = clamp01(iv.x) * msx;
        o2.y = clamp01(iv.y) * msy;
        o2.z = clamp01(iv.z) * msz;
        o2.w = clamp01(iv.w) * msw;
        out0[q] = o0;
        out1[q] = o1;
        out3[q] = o1;
        out2[q] = o2;
    }
}

// ---------------------------------------------------------------------------
// Stage 2: LDS-privatized histograms of gathered samples.
// ghist[0..767]   = hist of ref_masked  (dst) per channel
// ghist[768..1535]= hist of target_masked (ref) per channel
// ---------------------------------------------------------------------------
__global__ void k_hist(const float* __restrict__ rfp, const float* __restrict__ tar,
                       const float* __restrict__ msrc, const float* __restrict__ mtar,
                       const int* __restrict__ i0, const int* __restrict__ i1,
                       const int* __restrict__ i2, const int* __restrict__ i3,
                       unsigned int* __restrict__ ghist, int n)
{
    __shared__ unsigned int h[2 * 3 * NB];
    for (int i = threadIdx.x; i < 2 * 3 * NB; i += blockDim.x) h[i] = 0u;
    __syncthreads();

    for (int k = blockIdx.x * blockDim.x + threadIdx.x; k < n; k += gridDim.x * blockDim.x) {
        int pd = i0[k] * H + i1[k];
        int pr = i2[k] * H + i3[k];
        float md = msrc[pd] / 255.0f;
        float mr = mtar[pr] / 255.0f;
#pragma unroll
        for (int c = 0; c < 3; ++c) {
            float rv = rfp[c * HH + pd];
            float v  = clamp01((rv + 1.0f) * 0.5f) * 255.0f * md;   // ref_masked value
            int b = min(max((int)v, 0), NB - 1);
            atomicAdd(&h[c * NB + b], 1u);
            float tv = tar[c * HH + pr];
            float w  = clamp01((tv + 1.0f) * 0.5f) * 255.0f * mr;   // target_masked value
            int b2 = min(max((int)w, 0), NB - 1);
            atomicAdd(&h[3 * NB + c * NB + b2], 1u);
        }
    }
    __syncthreads();
    for (int i = threadIdx.x; i < 2 * 3 * NB; i += blockDim.x) {
        unsigned int v = h[i];
        if (v) atomicAdd(&ghist[i], v);
    }
}

// ---------------------------------------------------------------------------
// Stage 3: cdfs + transfer tables. ONE block of 384 threads = 6 waves.
// Wave w owns histogram w (0-2: dst per channel, 3-5: ref per channel).
// Lane holds 4 consecutive bins (uint4 coalesced load) -> register scan of 4
// -> wave-wide Hillis-Steele shfl_up scan (integer, bit-exact vs serial sum)
// -> float divide by total (identical numerics to reference cdf).
// ---------------------------------------------------------------------------
__global__ void k_tables(const uint4* __restrict__ ghist4, float* __restrict__ table)
{
    __shared__ float cdf[6][NB];     // rows 0-2: cdf_dst, rows 3-5: cdf_ref
    int t = threadIdx.x;
    int wave = t >> 6, lane = t & 63;

    // one uint4 per lane: bins [lane*4 .. lane*4+3] of histogram `wave`
    uint4 v = ghist4[wave * 64 + lane];
    unsigned int s0 = v.x;
    unsigned int s1 = s0 + v.y;
    unsigned int s2 = s1 + v.z;
    unsigned int s3 = s2 + v.w;

    // inclusive wave scan of the per-lane sums
    unsigned int scan = s3;
#pragma unroll
    for (int off = 1; off < 64; off <<= 1) {
        unsigned int u = (unsigned int)__shfl_up((int)scan, off, 64);
        if (lane >= off) scan += u;
    }
    unsigned int prefix = scan - s3;                       // exclusive prefix
    unsigned int total  = (unsigned int)__shfl((int)scan, 63, 64);
    float ft = (float)total;

    cdf[wave][lane * 4 + 0] = (float)(prefix + s0) / ft;
    cdf[wave][lane * 4 + 1] = (float)(prefix + s1) / ft;
    cdf[wave][lane * 4 + 2] = (float)(prefix + s2) / ft;
    cdf[wave][lane * 4 + 3] = (float)(prefix + s3) / ft;
    __syncthreads();

    // transfer-table search: threads 0..255, one bin each, 3 channels
    if (t < NB) {
#pragma unroll
        for (int c = 0; c < 3; ++c) {
            float r = cdf[c][t];
            int tab = t;
            for (int j = 0; j < NB - 1; ++j) {
                if (r >= cdf[3 + c][j] && r <= cdf[3 + c][j + 1]) { tab = j + 1; break; }
            }
            if (t == NB - 1) tab = NB - 1;
            table[c * NB + t] = (float)tab;
        }
    }
}

// ---------------------------------------------------------------------------
// Stage 4: scatter matched values into out3.
// Duplicate (i0,i1) pairs write identical values -> benign race.
// ---------------------------------------------------------------------------
__global__ void k_scatter(const float* __restrict__ rfp, const float* __restrict__ msrc,
                          const int* __restrict__ i0, const int* __restrict__ i1,
                          const float* __restrict__ table, float* __restrict__ out3, int n)
{
    int k = blockIdx.x * blockDim.x + threadIdx.x;
    if (k >= n) return;
    int pd = i0[k] * H + i1[k];
    float md = msrc[pd] / 255.0f;
#pragma unroll
    for (int c = 0; c < 3; ++c) {
        float rv = rfp[c * HH + pd];
        float v  = clamp01((rv + 1.0f) * 0.5f) * 255.0f * md;
        int b = min(max((int)v, 0), NB - 1);
        out3[c * HH + pd] = table[c * NB + b] / 255.0f;
    }
}

// ---------------------------------------------------------------------------
// Stage 5: loss = mean |out2 - out3| over 3*H*H elements.
// ---------------------------------------------------------------------------
__global__ void k_loss(const float4* __restrict__ a, const float4* __restrict__ b,
                       float* __restrict__ loss)
{
    float s = 0.0f;
    int n4 = CHW / 4;
    for (int i = blockIdx.x * blockDim.x + threadIdx.x; i < n4; i += gridDim.x * blockDim.x) {
        float4 x = a[i], y = b[i];
        s += fabsf(x.x - y.x) + fabsf(x.y - y.y) + fabsf(x.z - y.z) + fabsf(x.w - y.w);
    }
#pragma unroll
    for (int off = 32; off > 0; off >>= 1) s += __shfl_down(s, off);
    __shared__ float ws[4];
    int lane = threadIdx.x & 63, w = threadIdx.x >> 6;
    if (lane == 0) ws[w] = s;
    __syncthreads();
    if (threadIdx.x == 0) {
        float tsum = ws[0] + ws[1] + ws[2] + ws[3];
        atomicAdd(loss, tsum * (1.0f / (float)CHW));
    }
}

extern "C" void kernel_launch(void* const* d_in, const int* in_sizes, int n_in,
                              void* d_out, int out_size, void* d_ws, size_t ws_size,
                              hipStream_t stream)
{
    const float* inp  = (const float*)d_in[0];
    const float* tar  = (const float*)d_in[1];
    const float* rfp  = (const float*)d_in[2];
    const float* msrc = (const float*)d_in[3];
    const float* mtar = (const float*)d_in[4];
    // d_in[5] = target_data_eye (unused by the reference computation)
    const int* i0 = (const int*)d_in[6];
    const int* i1 = (const int*)d_in[7];
    const int* i2 = (const int*)d_in[8];
    const int* i3 = (const int*)d_in[9];
    int n = in_sizes[6];

    float* out0 = (float*)d_out;
    float* out1 = out0 + CHW;
    float* out2 = out1 + CHW;
    float* out3 = out2 + CHW;
    float* loss = out3 + CHW;

    unsigned int* ghist = (unsigned int*)d_ws;            // 1536 u32
    float* table = (float*)((char*)d_ws + 1536 * sizeof(unsigned int)); // 768 f32

    hipMemsetAsync(d_ws, 0, 1536 * sizeof(unsigned int), stream);
    hipMemsetAsync(loss, 0, sizeof(float), stream);

    k_elementwise<<<(HH / 4 + 255) / 256, 256, 0, stream>>>(
        (const float4*)inp, (const float4*)tar, (const float4*)rfp,
        (const float4*)msrc, (const float4*)mtar,
        (float4*)out0, (float4*)out1, (float4*)out2, (float4*)out3);

    k_hist<<<256, 256, 0, stream>>>(rfp, tar, msrc, mtar, i0, i1, i2, i3, ghist, n);

    k_tables<<<1, 384, 0, stream>>>((const uint4*)ghist, table);

    k_scatter<<<(n + 255) / 256, 256, 0, stream>>>(rfp, msrc, i0, i1, table, out3, n);

    k_loss<<<768, 256, 0, stream>>>((const float4*)out2, (const float4*)out3, loss);
}

// Round 3
// 235.572 us; speedup vs baseline: 1.3926x; 1.3251x over previous
//
#include <hip/hip_runtime.h>

#define H 1024
#define HH (H * H)          // 1048576 per channel plane
#define CHW (3 * HH)        // 3145728 per image
#define NB 256

__device__ __forceinline__ float clamp01(float x) { return fminf(fmaxf(x, 0.0f), 1.0f); }

// ---------------------------------------------------------------------------
// Stage 1: elementwise masking.
// out0 = target_masked/255 = clip((t+1)/2,0,1) * (mask_tar/255)
// out1 = ref_masked/255    = clip((r+1)/2,0,1) * (mask_src/255)
// out2 = input_masked/255  = clip(i,0,1)       * (mask_src/255)
// out3 = out1 (base for the scatter of matched values)
// ---------------------------------------------------------------------------
__global__ void k_elementwise(const float4* __restrict__ inp,
                              const float4* __restrict__ tar,
                              const float4* __restrict__ rfp,
                              const float4* __restrict__ msrc,
                              const float4* __restrict__ mtar,
                              float4* __restrict__ out0, float4* __restrict__ out1,
                              float4* __restrict__ out2, float4* __restrict__ out3)
{
    int p = blockIdx.x * blockDim.x + threadIdx.x;
    if (p >= HH / 4) return;
    float4 ms4 = msrc[p], mt4 = mtar[p];
    // true division: 255.0f/255.0f == 1.0f exactly (mul by 1/255f would give 1+ulp)
    float msx = ms4.x / 255.0f, msy = ms4.y / 255.0f, msz = ms4.z / 255.0f, msw = ms4.w / 255.0f;
    float mtx = mt4.x / 255.0f, mty = mt4.y / 255.0f, mtz = mt4.z / 255.0f, mtw = mt4.w / 255.0f;
#pragma unroll
    for (int c = 0; c < 3; ++c) {
        int q = c * (HH / 4) + p;
        float4 t = tar[q], r = rfp[q], iv = inp[q];
        float4 o0, o1, o2;
        o0.x = clamp01((t.x + 1.0f) * 0.5f) * mtx;
        o0.y = clamp01((t.y + 1.0f) * 0.5f) * mty;
        o0.z = clamp01((t.z + 1.0f) * 0.5f) * mtz;
        o0.w = clamp01((t.w + 1.0f) * 0.5f) * mtw;
        o1.x = clamp01((r.x + 1.0f) * 0.5f) * msx;
        o1.y = clamp01((r.y + 1.0f) * 0.5f) * msy;
        o1.z = clamp01((r.z + 1.0f) * 0.5f) * msz;
        o1.w = clamp01((r.w + 1.0f) * 0.5f) * msw;
        o2.x = clamp01(iv.x) * msx;
        o2.y = clamp01(iv.y) * msy;
        o2.z = clamp01(iv.z) * msz;
        o2.w = clamp01(iv.w) * msw;
        out0[q] = o0;
        out1[q] = o1;
        out3[q] = o1;
        out2[q] = o2;
    }
}

// ---------------------------------------------------------------------------
// Stage 2: LDS-privatized histograms of gathered samples.
// ghist[0..767]   = hist of ref_masked  (dst) per channel
// ghist[768..1535]= hist of target_masked (ref) per channel
// ---------------------------------------------------------------------------
__global__ void k_hist(const float* __restrict__ rfp, const float* __restrict__ tar,
                       const float* __restrict__ msrc, const float* __restrict__ mtar,
                       const int* __restrict__ i0, const int* __restrict__ i1,
                       const int* __restrict__ i2, const int* __restrict__ i3,
                       unsigned int* __restrict__ ghist, int n)
{
    __shared__ unsigned int h[2 * 3 * NB];
    for (int i = threadIdx.x; i < 2 * 3 * NB; i += blockDim.x) h[i] = 0u;
    __syncthreads();

    for (int k = blockIdx.x * blockDim.x + threadIdx.x; k < n; k += gridDim.x * blockDim.x) {
        int pd = i0[k] * H + i1[k];
        int pr = i2[k] * H + i3[k];
        float md = msrc[pd] / 255.0f;
        float mr = mtar[pr] / 255.0f;
#pragma unroll
        for (int c = 0; c < 3; ++c) {
            float rv = rfp[c * HH + pd];
            float v  = clamp01((rv + 1.0f) * 0.5f) * 255.0f * md;   // ref_masked value
            int b = min(max((int)v, 0), NB - 1);
            atomicAdd(&h[c * NB + b], 1u);
            float tv = tar[c * HH + pr];
            float w  = clamp01((tv + 1.0f) * 0.5f) * 255.0f * mr;   // target_masked value
            int b2 = min(max((int)w, 0), NB - 1);
            atomicAdd(&h[3 * NB + c * NB + b2], 1u);
        }
    }
    __syncthreads();
    for (int i = threadIdx.x; i < 2 * 3 * NB; i += blockDim.x) {
        unsigned int v = h[i];
        if (v) atomicAdd(&ghist[i], v);
    }
}

// ---------------------------------------------------------------------------
// Stage 3: cdfs + transfer tables. ONE block of 384 threads = 6 waves.
// Wave w owns histogram w (0-2: dst per channel, 3-5: ref per channel).
// CDF: uint4 load -> register scan of 4 -> wave shfl_up scan (integer,
// bit-exact vs serial sum) -> float divide by total.
// Table: cdf_ref is monotone, so "first j with lo<=r<=hi" ==
// lower_bound(cdf_ref[1..255], r)-1 with identity fallback when
// j*==0 && cdf_ref[0] > r. 8-step binary search replaces the ~255-step
// serially-dependent LDS chain that cost 80us.
// ---------------------------------------------------------------------------
__global__ void k_tables(const uint4* __restrict__ ghist4, float* __restrict__ table)
{
    __shared__ float cdf[6][NB];     // rows 0-2: cdf_dst, rows 3-5: cdf_ref
    int t = threadIdx.x;
    int wave = t >> 6, lane = t & 63;

    // one uint4 per lane: bins [lane*4 .. lane*4+3] of histogram `wave`
    uint4 v = ghist4[wave * 64 + lane];
    unsigned int s0 = v.x;
    unsigned int s1 = s0 + v.y;
    unsigned int s2 = s1 + v.z;
    unsigned int s3 = s2 + v.w;

    // inclusive wave scan of the per-lane sums
    unsigned int scan = s3;
#pragma unroll
    for (int off = 1; off < 64; off <<= 1) {
        unsigned int u = (unsigned int)__shfl_up((int)scan, off, 64);
        if (lane >= off) scan += u;
    }
    unsigned int prefix = scan - s3;                       // exclusive prefix
    unsigned int total  = (unsigned int)__shfl((int)scan, 63, 64);
    float ft = (float)total;

    cdf[wave][lane * 4 + 0] = (float)(prefix + s0) / ft;
    cdf[wave][lane * 4 + 1] = (float)(prefix + s1) / ft;
    cdf[wave][lane * 4 + 2] = (float)(prefix + s2) / ft;
    cdf[wave][lane * 4 + 3] = (float)(prefix + s3) / ft;
    __syncthreads();

    // transfer-table search: threads 0..255, one bin each, 3 channels
    if (t < NB) {
#pragma unroll
        for (int c = 0; c < 3; ++c) {
            float r = cdf[c][t];
            const float* cr = cdf[3 + c];
            // first m in [1,255] with cr[m] >= r (cr[255]==1.0 >= r always)
            int lo = 1, hi = NB - 1;
#pragma unroll
            for (int it = 0; it < 8; ++it) {
                int mid = (lo + hi) >> 1;
                if (cr[mid] >= r) hi = mid; else lo = mid + 1;
            }
            int jstar = lo - 1;
            int tab = (jstar == 0 && cr[0] > r) ? t : (jstar + 1);
            if (t == NB - 1) tab = NB - 1;
            table[c * NB + t] = (float)tab;
        }
    }
}

// ---------------------------------------------------------------------------
// Stage 4: scatter matched values into out3.
// Duplicate (i0,i1) pairs write identical values -> benign race.
// ---------------------------------------------------------------------------
__global__ void k_scatter(const float* __restrict__ rfp, const float* __restrict__ msrc,
                          const int* __restrict__ i0, const int* __restrict__ i1,
                          const float* __restrict__ table, float* __restrict__ out3, int n)
{
    int k = blockIdx.x * blockDim.x + threadIdx.x;
    if (k >= n) return;
    int pd = i0[k] * H + i1[k];
    float md = msrc[pd] / 255.0f;
#pragma unroll
    for (int c = 0; c < 3; ++c) {
        float rv = rfp[c * HH + pd];
        float v  = clamp01((rv + 1.0f) * 0.5f) * 255.0f * md;
        int b = min(max((int)v, 0), NB - 1);
        out3[c * HH + pd] = table[c * NB + b] / 255.0f;
    }
}

// ---------------------------------------------------------------------------
// Stage 5: loss = mean |out2 - out3| over 3*H*H elements.
// ---------------------------------------------------------------------------
__global__ void k_loss(const float4* __restrict__ a, const float4* __restrict__ b,
                       float* __restrict__ loss)
{
    float s = 0.0f;
    int n4 = CHW / 4;
    for (int i = blockIdx.x * blockDim.x + threadIdx.x; i < n4; i += gridDim.x * blockDim.x) {
        float4 x = a[i], y = b[i];
        s += fabsf(x.x - y.x) + fabsf(x.y - y.y) + fabsf(x.z - y.z) + fabsf(x.w - y.w);
    }
#pragma unroll
    for (int off = 32; off > 0; off >>= 1) s += __shfl_down(s, off);
    __shared__ float ws[4];
    int lane = threadIdx.x & 63, w = threadIdx.x >> 6;
    if (lane == 0) ws[w] = s;
    __syncthreads();
    if (threadIdx.x == 0) {
        float tsum = ws[0] + ws[1] + ws[2] + ws[3];
        atomicAdd(loss, tsum * (1.0f / (float)CHW));
    }
}

extern "C" void kernel_launch(void* const* d_in, const int* in_sizes, int n_in,
                              void* d_out, int out_size, void* d_ws, size_t ws_size,
                              hipStream_t stream)
{
    const float* inp  = (const float*)d_in[0];
    const float* tar  = (const float*)d_in[1];
    const float* rfp  = (const float*)d_in[2];
    const float* msrc = (const float*)d_in[3];
    const float* mtar = (const float*)d_in[4];
    // d_in[5] = target_data_eye (unused by the reference computation)
    const int* i0 = (const int*)d_in[6];
    const int* i1 = (const int*)d_in[7];
    const int* i2 = (const int*)d_in[8];
    const int* i3 = (const int*)d_in[9];
    int n = in_sizes[6];

    float* out0 = (float*)d_out;
    float* out1 = out0 + CHW;
    float* out2 = out1 + CHW;
    float* out3 = out2 + CHW;
    float* loss = out3 + CHW;

    unsigned int* ghist = (unsigned int*)d_ws;            // 1536 u32
    float* table = (float*)((char*)d_ws + 1536 * sizeof(unsigned int)); // 768 f32

    hipMemsetAsync(d_ws, 0, 1536 * sizeof(unsigned int), stream);
    hipMemsetAsync(loss, 0, sizeof(float), stream);

    k_elementwise<<<(HH / 4 + 255) / 256, 256, 0, stream>>>(
        (const float4*)inp, (const float4*)tar, (const float4*)rfp,
        (const float4*)msrc, (const float4*)mtar,
        (float4*)out0, (float4*)out1, (float4*)out2, (float4*)out3);

    k_hist<<<256, 256, 0, stream>>>(rfp, tar, msrc, mtar, i0, i1, i2, i3, ghist, n);

    k_tables<<<1, 384, 0, stream>>>((const uint4*)ghist, table);

    k_scatter<<<(n + 255) / 256, 256, 0, stream>>>(rfp, msrc, i0, i1, table, out3, n);

    k_loss<<<768, 256, 0, stream>>>((const float4*)out2, (const float4*)out3, loss);
}

// Round 4
// 192.537 us; speedup vs baseline: 1.7039x; 1.2235x over previous
//
#include <hip/hip_runtime.h>

#define H 1024
#define HH (H * H)          // 1048576 per channel plane
#define CHW (3 * HH)        // 3145728 per image
#define NB 256

__device__ __forceinline__ float clamp01(float x) { return fminf(fmaxf(x, 0.0f), 1.0f); }

// bin of a value already divided by 255 (v01 = masked_value/255, mask in {0,1})
// (int)(v01*255) is bit-exact vs reference's (int)(clamp01(..)*255*mask):
// mask multiply by exactly 1.0f/0.0f commutes exactly.
__device__ __forceinline__ unsigned int bin8(float v01) {
    int b = (int)(v01 * 255.0f);
    return (unsigned int)min(max(b, 0), NB - 1);
}

// ---------------------------------------------------------------------------
// Stage 1: elementwise masking + packed per-pixel bin triples.
// out0 = target_masked/255, out1 = ref_masked/255, out2 = input_masked/255,
// out3 = out1. pk_dst[p] = 3 bins of ref_masked (b|g<<8|r<<16),
// pk_ref[p] = 3 bins of target_masked. 4 pixels per thread (float4).
// ---------------------------------------------------------------------------
__global__ void k_elementwise(const float4* __restrict__ inp,
                              const float4* __restrict__ tar,
                              const float4* __restrict__ rfp,
                              const float4* __restrict__ msrc,
                              const float4* __restrict__ mtar,
                              float4* __restrict__ out0, float4* __restrict__ out1,
                              float4* __restrict__ out2, float4* __restrict__ out3,
                              uint4* __restrict__ pk_dst, uint4* __restrict__ pk_ref)
{
    int p = blockIdx.x * blockDim.x + threadIdx.x;
    if (p >= HH / 4) return;
    float4 ms4 = msrc[p], mt4 = mtar[p];
    // true division: 255.0f/255.0f == 1.0f exactly
    float msx = ms4.x / 255.0f, msy = ms4.y / 255.0f, msz = ms4.z / 255.0f, msw = ms4.w / 255.0f;
    float mtx = mt4.x / 255.0f, mty = mt4.y / 255.0f, mtz = mt4.z / 255.0f, mtw = mt4.w / 255.0f;
    unsigned int bd0 = 0, bd1 = 0, bd2 = 0, bd3 = 0;   // packed dst bins, 4 pixels
    unsigned int br0 = 0, br1 = 0, br2 = 0, br3 = 0;   // packed ref bins
#pragma unroll
    for (int c = 0; c < 3; ++c) {
        int q = c * (HH / 4) + p;
        float4 t = tar[q], r = rfp[q], iv = inp[q];
        float4 o0, o1, o2;
        o0.x = clamp01((t.x + 1.0f) * 0.5f) * mtx;
        o0.y = clamp01((t.y + 1.0f) * 0.5f) * mty;
        o0.z = clamp01((t.z + 1.0f) * 0.5f) * mtz;
        o0.w = clamp01((t.w + 1.0f) * 0.5f) * mtw;
        o1.x = clamp01((r.x + 1.0f) * 0.5f) * msx;
        o1.y = clamp01((r.y + 1.0f) * 0.5f) * msy;
        o1.z = clamp01((r.z + 1.0f) * 0.5f) * msz;
        o1.w = clamp01((r.w + 1.0f) * 0.5f) * msw;
        o2.x = clamp01(iv.x) * msx;
        o2.y = clamp01(iv.y) * msy;
        o2.z = clamp01(iv.z) * msz;
        o2.w = clamp01(iv.w) * msw;
        out0[q] = o0;
        out1[q] = o1;
        out3[q] = o1;
        out2[q] = o2;
        int sh = 8 * c;
        bd0 |= bin8(o1.x) << sh;  bd1 |= bin8(o1.y) << sh;
        bd2 |= bin8(o1.z) << sh;  bd3 |= bin8(o1.w) << sh;
        br0 |= bin8(o0.x) << sh;  br1 |= bin8(o0.y) << sh;
        br2 |= bin8(o0.z) << sh;  br3 |= bin8(o0.w) << sh;
    }
    pk_dst[p] = make_uint4(bd0, bd1, bd2, bd3);
    pk_ref[p] = make_uint4(br0, br1, br2, br3);
}

// ---------------------------------------------------------------------------
// Stage 2: histograms from packed bins. One 4B gather per sample per side
// over 4MB arrays (fit in a per-XCD L2). 784x512 for ~24 waves/CU.
// ---------------------------------------------------------------------------
__global__ void k_hist(const unsigned int* __restrict__ pk_dst,
                       const unsigned int* __restrict__ pk_ref,
                       const int* __restrict__ i0, const int* __restrict__ i1,
                       const int* __restrict__ i2, const int* __restrict__ i3,
                       unsigned int* __restrict__ ghist, int n)
{
    __shared__ unsigned int h[2 * 3 * NB];
    for (int i = threadIdx.x; i < 2 * 3 * NB; i += blockDim.x) h[i] = 0u;
    __syncthreads();

    for (int k = blockIdx.x * blockDim.x + threadIdx.x; k < n; k += gridDim.x * blockDim.x) {
        int pd = i0[k] * H + i1[k];
        int pr = i2[k] * H + i3[k];
        unsigned int a = pk_dst[pd];
        unsigned int b = pk_ref[pr];
        atomicAdd(&h[        (a       & 255u)], 1u);
        atomicAdd(&h[  NB + ((a >> 8) & 255u)], 1u);
        atomicAdd(&h[2*NB + ((a >>16) & 255u)], 1u);
        atomicAdd(&h[3*NB + ( b       & 255u)], 1u);
        atomicAdd(&h[4*NB + ((b >> 8) & 255u)], 1u);
        atomicAdd(&h[5*NB + ((b >>16) & 255u)], 1u);
    }
    __syncthreads();
    for (int i = threadIdx.x; i < 2 * 3 * NB; i += blockDim.x) {
        unsigned int v = h[i];
        if (v) atomicAdd(&ghist[i], v);
    }
}

// ---------------------------------------------------------------------------
// Stage 3: cdfs + transfer tables. ONE block of 384 threads = 6 waves.
// CDF: uint4 load -> register scan of 4 -> wave shfl_up scan (integer,
// bit-exact) -> float divide by total. Table via 8-step binary search
// (cdf_ref monotone; identical comparisons to the reference's first-hit).
// Table stored PRE-DIVIDED by 255 (same single fp divide the reference does).
// ---------------------------------------------------------------------------
__global__ void k_tables(const uint4* __restrict__ ghist4, float* __restrict__ table)
{
    __shared__ float cdf[6][NB];     // rows 0-2: cdf_dst, rows 3-5: cdf_ref
    int t = threadIdx.x;
    int wave = t >> 6, lane = t & 63;

    uint4 v = ghist4[wave * 64 + lane];
    unsigned int s0 = v.x;
    unsigned int s1 = s0 + v.y;
    unsigned int s2 = s1 + v.z;
    unsigned int s3 = s2 + v.w;

    unsigned int scan = s3;
#pragma unroll
    for (int off = 1; off < 64; off <<= 1) {
        unsigned int u = (unsigned int)__shfl_up((int)scan, off, 64);
        if (lane >= off) scan += u;
    }
    unsigned int prefix = scan - s3;
    unsigned int total  = (unsigned int)__shfl((int)scan, 63, 64);
    float ft = (float)total;

    cdf[wave][lane * 4 + 0] = (float)(prefix + s0) / ft;
    cdf[wave][lane * 4 + 1] = (float)(prefix + s1) / ft;
    cdf[wave][lane * 4 + 2] = (float)(prefix + s2) / ft;
    cdf[wave][lane * 4 + 3] = (float)(prefix + s3) / ft;
    __syncthreads();

    if (t < NB) {
#pragma unroll
        for (int c = 0; c < 3; ++c) {
            float r = cdf[c][t];
            const float* cr = cdf[3 + c];
            int lo = 1, hi = NB - 1;
#pragma unroll
            for (int it = 0; it < 8; ++it) {
                int mid = (lo + hi) >> 1;
                if (cr[mid] >= r) hi = mid; else lo = mid + 1;
            }
            int jstar = lo - 1;
            int tab = (jstar == 0 && cr[0] > r) ? t : (jstar + 1);
            if (t == NB - 1) tab = NB - 1;
            table[c * NB + t] = (float)tab / 255.0f;
        }
    }
}

// ---------------------------------------------------------------------------
// Stage 4: scatter table-mapped values into out3 using packed bins.
// Table (768 f32, pre-divided) staged in LDS. Duplicate pixels write
// identical values -> benign race.
// ---------------------------------------------------------------------------
__global__ void k_scatter(const unsigned int* __restrict__ pk_dst,
                          const int* __restrict__ i0, const int* __restrict__ i1,
                          const float* __restrict__ table, float* __restrict__ out3, int n)
{
    __shared__ float tl[3 * NB];
    for (int i = threadIdx.x; i < 3 * NB; i += blockDim.x) tl[i] = table[i];
    __syncthreads();
    int k = blockIdx.x * blockDim.x + threadIdx.x;
    if (k >= n) return;
    int pd = i0[k] * H + i1[k];
    unsigned int a = pk_dst[pd];
    out3[         pd] = tl[        (a       & 255u)];
    out3[HH     + pd] = tl[  NB + ((a >> 8) & 255u)];
    out3[2 * HH + pd] = tl[2*NB + ((a >>16) & 255u)];
}

// ---------------------------------------------------------------------------
// Stage 5: loss = mean |out2 - out3| over 3*H*H elements.
// ---------------------------------------------------------------------------
__global__ void k_loss(const float4* __restrict__ a, const float4* __restrict__ b,
                       float* __restrict__ loss)
{
    float s = 0.0f;
    int n4 = CHW / 4;
    for (int i = blockIdx.x * blockDim.x + threadIdx.x; i < n4; i += gridDim.x * blockDim.x) {
        float4 x = a[i], y = b[i];
        s += fabsf(x.x - y.x) + fabsf(x.y - y.y) + fabsf(x.z - y.z) + fabsf(x.w - y.w);
    }
#pragma unroll
    for (int off = 32; off > 0; off >>= 1) s += __shfl_down(s, off);
    __shared__ float ws[4];
    int lane = threadIdx.x & 63, w = threadIdx.x >> 6;
    if (lane == 0) ws[w] = s;
    __syncthreads();
    if (threadIdx.x == 0) {
        float tsum = ws[0] + ws[1] + ws[2] + ws[3];
        atomicAdd(loss, tsum * (1.0f / (float)CHW));
    }
}

extern "C" void kernel_launch(void* const* d_in, const int* in_sizes, int n_in,
                              void* d_out, int out_size, void* d_ws, size_t ws_size,
                              hipStream_t stream)
{
    const float* inp  = (const float*)d_in[0];
    const float* tar  = (const float*)d_in[1];
    const float* rfp  = (const float*)d_in[2];
    const float* msrc = (const float*)d_in[3];
    const float* mtar = (const float*)d_in[4];
    // d_in[5] = target_data_eye (unused by the reference computation)
    const int* i0 = (const int*)d_in[6];
    const int* i1 = (const int*)d_in[7];
    const int* i2 = (const int*)d_in[8];
    const int* i3 = (const int*)d_in[9];
    int n = in_sizes[6];

    float* out0 = (float*)d_out;
    float* out1 = out0 + CHW;
    float* out2 = out1 + CHW;
    float* out3 = out2 + CHW;
    float* loss = out3 + CHW;

    // workspace layout (needs 6KB + 3KB + pad + 2*4MB ≈ 8.02 MB)
    unsigned int* ghist  = (unsigned int*)d_ws;                        // 1536 u32
    float*        table  = (float*)((char*)d_ws + 6144);               // 768 f32
    unsigned int* pk_dst = (unsigned int*)((char*)d_ws + 16384);       // HH u32
    unsigned int* pk_ref = pk_dst + HH;                                // HH u32

    hipMemsetAsync(ghist, 0, 1536 * sizeof(unsigned int), stream);
    hipMemsetAsync(loss, 0, sizeof(float), stream);

    k_elementwise<<<(HH / 4 + 255) / 256, 256, 0, stream>>>(
        (const float4*)inp, (const float4*)tar, (const float4*)rfp,
        (const float4*)msrc, (const float4*)mtar,
        (float4*)out0, (float4*)out1, (float4*)out2, (float4*)out3,
        (uint4*)pk_dst, (uint4*)pk_ref);

    k_hist<<<784, 512, 0, stream>>>(pk_dst, pk_ref, i0, i1, i2, i3, ghist, n);

    k_tables<<<1, 384, 0, stream>>>((const uint4*)ghist, table);

    k_scatter<<<(n + 255) / 256, 256, 0, stream>>>(pk_dst, i0, i1, table, out3, n);

    k_loss<<<768, 256, 0, stream>>>((const float4*)out2, (const float4*)out3, loss);
}